// Round 5
// baseline (607.562 us; speedup 1.0000x reference)
//
#include <hip/hip_runtime.h>
#include <hip/hip_bf16.h>

typedef __attribute__((ext_vector_type(4))) float f32x4;
typedef __attribute__((ext_vector_type(4))) int   i32x4;
typedef __attribute__((ext_vector_type(8))) short s16x8;
typedef __attribute__((ext_vector_type(4))) unsigned short u16x4;
typedef __attribute__((ext_vector_type(2))) unsigned int  u32x2;

#define T_ 512
#define B_ 8
#define H_ 128
#define V_ 32000

// round-to-nearest-even f32 -> bf16
__device__ __forceinline__ unsigned short f2b(float f) {
  unsigned int u = __float_as_uint(f);
  u = (u + 0x7FFFu + ((u >> 16) & 1u)) >> 16;
  return (unsigned short)u;
}

__device__ __forceinline__ float hsum4(f32x4 v) { return (v.x + v.y) + (v.z + v.w); }

__device__ __forceinline__ float tanh_fast(float x) {
  float e = __expf(2.f * x);
  return 1.f - 2.f * __builtin_amdgcn_rcpf(e + 1.f);
}

__device__ __forceinline__ f32x4 tanh4(f32x4 v) {
  f32x4 r;
  r.x = tanh_fast(v.x); r.y = tanh_fast(v.y);
  r.z = tanh_fast(v.z); r.w = tanh_fast(v.w);
  return r;
}

// pack 4 f32 -> 4 bf16 (2 dwords) via v_cvt_pk_bf16_f32
__device__ __forceinline__ u32x2 pk4(f32x4 v) {
  unsigned int a, b;
  asm("v_cvt_pk_bf16_f32 %0, %1, %2" : "=v"(a) : "v"(v.x), "v"(v.y));
  asm("v_cvt_pk_bf16_f32 %0, %1, %2" : "=v"(b) : "v"(v.z), "v"(v.w));
  u32x2 r; r.x = a; r.y = b; return r;
}

// barrier that does NOT drain vmcnt: LDS-only visibility + s_barrier.
__device__ __forceinline__ void lds_barrier() {
  asm volatile("s_waitcnt lgkmcnt(0)\n\ts_barrier" ::: "memory");
}

// ---------------- fc_W f32 -> bf16 ----------------
__global__ __launch_bounds__(256) void convert_w_kernel(const float* __restrict__ src,
                                                        unsigned short* __restrict__ dst, int n4) {
  int idx = blockIdx.x * 256 + threadIdx.x;
  int stride = gridDim.x * 256;
  for (int c = idx; c < n4; c += stride) {
    f32x4 v = ((const f32x4*)src)[c];
    u16x4 o;
    o.x = f2b(v.x); o.y = f2b(v.y); o.z = f2b(v.z); o.w = f2b(v.w);
    ((u16x4*)dst)[c] = o;
  }
}

// ---------------- pre0 = emb[x] @ W_ih0^T + b_ih0 + b_hh0 ----------------
__global__ __launch_bounds__(128) void pre_kernel(const float* __restrict__ emb,
                                                  const int* __restrict__ x,
                                                  const float* __restrict__ W,
                                                  const float* __restrict__ b1,
                                                  const float* __restrict__ b2,
                                                  float* __restrict__ out) {
  const int tid = threadIdx.x;
  __shared__ alignas(16) float lds_in[H_];
  f32x4 w[32];
#pragma unroll
  for (int r = 0; r < 32; ++r) w[r] = *(const f32x4*)(W + tid * H_ + 4 * r);
  const float bsum = b1[tid] + b2[tid];
  const int m0 = blockIdx.x * 16;

  auto src_row = [&](int m) -> const float* {
    int t = m >> 3, b = m & 7;
    int tok = x[(b << 9) + t];          // x is [B,T]
    return emb + (size_t)tok * H_;
  };

  float stage = src_row(m0)[tid];
  for (int rr = 0; rr < 16; ++rr) {
    const int m = m0 + rr;
    lds_in[tid] = stage;
    __syncthreads();
    if (rr + 1 < 16) stage = src_row(m0 + rr + 1)[tid];
    f32x4 acc4 = {0.f, 0.f, 0.f, 0.f};
#pragma unroll
    for (int r = 0; r < 32; ++r) {
      f32x4 hv = *(const f32x4*)(lds_in + 4 * r);
      acc4 = __builtin_elementwise_fma(hv, w[r], acc4);
    }
    out[m * H_ + tid] = hsum4(acc4) + bsum;
    __syncthreads();
  }
}

// ---------------- fused dual-layer scan, v4: MFMA ----------------
// ONE block, 12 waves = 3 stages x 4 waves. All 8 batches in the MFMA N-dim.
// Per stage per step: y[128 m][8 n] = W . h as 8 M-tiles x 4 K-tiles of
// mfma_f32_16x16x32_bf16, W split hi+lo (weight quant error ~2^-17; only h
// carries bf16 noise). Wave w owns M-tiles {2w,2w+1}: 16 frags = 64 VGPR.
//   stage 0: h0[s]    = tanh(pre0[s] + W_hh0.h0[s-1])       s in [0,512)
//   stage 1: pih[s-1] = W_ih1.h0[s-1] + b_ih1 + b_hh1       s in [1,512]
//   stage 2: h1[s-2]  = tanh(pih[s-2] + W_hh1.h1[s-3])      s in [2,514)
// h bf16 in LDS [16 n][136 k] (pad -> balanced banks); B-frag: lane(n=l&15,
// g=l>>4) reads 8 bf16 at [n][kt*32+g*8]. D layout: col=l&15=n, row=g*4+reg.
// pih handed off as raw f32 D-fragments. One vmcnt-preserving lds_barrier
// per region; pre0 prefetch depth 2 stays in flight across it.
#define MM8(HF, BF0, BF1, BF2, BF3, CIN, OUT) { \
  f32x4 aA_ = (CIN), aB_ = {0.f, 0.f, 0.f, 0.f}; \
  aA_ = __builtin_amdgcn_mfma_f32_16x16x32_bf16(whi[HF][0], (BF0), aA_, 0, 0, 0); \
  aA_ = __builtin_amdgcn_mfma_f32_16x16x32_bf16(wlo[HF][0], (BF0), aA_, 0, 0, 0); \
  aA_ = __builtin_amdgcn_mfma_f32_16x16x32_bf16(whi[HF][1], (BF1), aA_, 0, 0, 0); \
  aA_ = __builtin_amdgcn_mfma_f32_16x16x32_bf16(wlo[HF][1], (BF1), aA_, 0, 0, 0); \
  aB_ = __builtin_amdgcn_mfma_f32_16x16x32_bf16(whi[HF][2], (BF2), aB_, 0, 0, 0); \
  aB_ = __builtin_amdgcn_mfma_f32_16x16x32_bf16(wlo[HF][2], (BF2), aB_, 0, 0, 0); \
  aB_ = __builtin_amdgcn_mfma_f32_16x16x32_bf16(whi[HF][3], (BF3), aB_, 0, 0, 0); \
  aB_ = __builtin_amdgcn_mfma_f32_16x16x32_bf16(wlo[HF][3], (BF3), aB_, 0, 0, 0); \
  (OUT) = aA_ + aB_; }

#define REGION(S, P0, P1) { \
  const int s_ = (S); \
  const int rd = (s_ + 1) & 1, wr = s_ & 1; \
  if (stage == 0) { \
    if (s_ < T_) { \
      s16x8 b0 = *(const s16x8*)&h0_l[rd][n][g * 8]; \
      s16x8 b1 = *(const s16x8*)&h0_l[rd][n][32 + g * 8]; \
      s16x8 b2 = *(const s16x8*)&h0_l[rd][n][64 + g * 8]; \
      s16x8 b3 = *(const s16x8*)&h0_l[rd][n][96 + g * 8]; \
      f32x4 v0, v1; \
      MM8(0, b0, b1, b2, b3, P0, v0) \
      MM8(1, b0, b1, b2, b3, P1, v1) \
      v0 = tanh4(v0); v1 = tanh4(v1); \
      *(u32x2*)&h0_l[wr][n][m0 + g * 4] = pk4(v0); \
      *(u32x2*)&h0_l[wr][n][m0 + 16 + g * 4] = pk4(v1); \
    } \
    int sn = s_ + 2; if (sn > T_ - 1) sn = T_ - 1; \
    P0 = *(const f32x4*)(pre0 + (sn * B_ + nn) * H_ + m0 + g * 4); \
    P1 = *(const f32x4*)(pre0 + (sn * B_ + nn) * H_ + m0 + 16 + g * 4); \
  } else if (stage == 1) { \
    if (s_ >= 1 && s_ <= T_) { \
      s16x8 b0 = *(const s16x8*)&h0_l[rd][n][g * 8]; \
      s16x8 b1 = *(const s16x8*)&h0_l[rd][n][32 + g * 8]; \
      s16x8 b2 = *(const s16x8*)&h0_l[rd][n][64 + g * 8]; \
      s16x8 b3 = *(const s16x8*)&h0_l[rd][n][96 + g * 8]; \
      f32x4 v0, v1; \
      MM8(0, b0, b1, b2, b3, bias0, v0) \
      MM8(1, b0, b1, b2, b3, bias1, v1) \
      *(f32x4*)&pih_l[rd][w][0][lane][0] = v0; \
      *(f32x4*)&pih_l[rd][w][1][lane][0] = v1; \
    } \
  } else { \
    if (s_ >= 2) { \
      s16x8 b0 = *(const s16x8*)&h1_l[rd][n][g * 8]; \
      s16x8 b1 = *(const s16x8*)&h1_l[rd][n][32 + g * 8]; \
      s16x8 b2 = *(const s16x8*)&h1_l[rd][n][64 + g * 8]; \
      s16x8 b3 = *(const s16x8*)&h1_l[rd][n][96 + g * 8]; \
      f32x4 c0 = *(const f32x4*)&pih_l[wr][w][0][lane][0]; \
      f32x4 c1 = *(const f32x4*)&pih_l[wr][w][1][lane][0]; \
      f32x4 v0, v1; \
      MM8(0, b0, b1, b2, b3, c0, v0) \
      MM8(1, b0, b1, b2, b3, c1, v1) \
      v0 = tanh4(v0); v1 = tanh4(v1); \
      u32x2 o0 = pk4(v0), o1 = pk4(v1); \
      *(u32x2*)&h1_l[wr][n][m0 + g * 4] = o0; \
      *(u32x2*)&h1_l[wr][n][m0 + 16 + g * 4] = o1; \
      if (n < 8) { \
        const int t = s_ - 2; \
        *(u32x2*)(h1b + (t * B_ + n) * H_ + m0 + g * 4) = o0; \
        *(u32x2*)(h1b + (t * B_ + n) * H_ + m0 + 16 + g * 4) = o1; \
      } \
    } \
  } \
  lds_barrier(); }

__global__ __launch_bounds__(768, 2) void fused_scan4(
    const float* __restrict__ pre0,
    const float* __restrict__ W_hh0,
    const float* __restrict__ W_ih1,
    const float* __restrict__ W_hh1,
    const float* __restrict__ b_ih1,
    const float* __restrict__ b_hh1,
    unsigned short* __restrict__ h1b) {
  const int tid   = threadIdx.x;
  const int wv    = tid >> 6;
  const int stage = wv >> 2;         // 0,1,2
  const int w     = wv & 3;          // wave within stage
  const int lane  = tid & 63;
  const int n     = lane & 15;       // batch column (valid < 8) / A-row index
  const int g     = lane >> 4;       // k-group (B) / row-group (D)
  const int m0    = w * 32;

  __shared__ unsigned short h0_l[2][16][136];
  __shared__ unsigned short h1_l[2][16][136];
  __shared__ alignas(16) float pih_l[2][4][2][64][4];

  for (int idx = tid; idx < 2 * 16 * 136; idx += 768) {
    ((unsigned short*)h0_l)[idx] = 0;
    ((unsigned short*)h1_l)[idx] = 0;
  }

  // A-fragments: W split hi+lo. lane: row m = m0+half*16+n, k = kt*32+g*8+j.
  const float* Wm = (stage == 0) ? W_hh0 : (stage == 1) ? W_ih1 : W_hh1;
  s16x8 whi[2][4], wlo[2][4];
#pragma unroll
  for (int half = 0; half < 2; ++half) {
#pragma unroll
    for (int kt = 0; kt < 4; ++kt) {
      const float* src = Wm + (m0 + half * 16 + n) * H_ + kt * 32 + g * 8;
      s16x8 hi, lo;
#pragma unroll
      for (int j = 0; j < 8; ++j) {
        float v = src[j];
        unsigned short hb = f2b(v);
        float resid = v - __uint_as_float(((unsigned int)hb) << 16);
        hi[j] = (short)hb;
        lo[j] = (short)f2b(resid);
      }
      whi[half][kt] = hi;
      wlo[half][kt] = lo;
    }
  }

  // stage-1 biases in D layout (m = m0 + half*16 + g*4 + r)
  f32x4 bias0 = {0.f, 0.f, 0.f, 0.f}, bias1 = {0.f, 0.f, 0.f, 0.f};
  if (stage == 1) {
    bias0 = *(const f32x4*)(b_ih1 + m0 + g * 4) + *(const f32x4*)(b_hh1 + m0 + g * 4);
    bias1 = *(const f32x4*)(b_ih1 + m0 + 16 + g * 4) + *(const f32x4*)(b_hh1 + m0 + 16 + g * 4);
  }

  const int nn = (n < 8) ? n : 7;   // clamped batch for pre0 loads (cols >=8 discarded)
  f32x4 preA0 = {0.f,0.f,0.f,0.f}, preA1 = {0.f,0.f,0.f,0.f};
  f32x4 preB0 = {0.f,0.f,0.f,0.f}, preB1 = {0.f,0.f,0.f,0.f};
  if (stage == 0) {
    preA0 = *(const f32x4*)(pre0 + (0 * B_ + nn) * H_ + m0 + g * 4);
    preA1 = *(const f32x4*)(pre0 + (0 * B_ + nn) * H_ + m0 + 16 + g * 4);
    preB0 = *(const f32x4*)(pre0 + (1 * B_ + nn) * H_ + m0 + g * 4);
    preB1 = *(const f32x4*)(pre0 + (1 * B_ + nn) * H_ + m0 + 16 + g * 4);
  }
  __syncthreads();

  for (int s2 = 0; s2 < T_ + 2; s2 += 2) {
    REGION(s2,     preA0, preA1)
    REGION(s2 + 1, preB0, preB1)
  }
}

// ---------------- logits = h1 @ fc_W^T + fc_b  (bf16 MFMA, v4) ----------------
// XCD-chunked grid: bid&7 = XCD, each XCD owns 32 consecutive v-tiles
// (1 MB fcW + 1 MB h1 -> L2-resident per XCD); m-inner within chunk so the
// same fcW tile is reused by 32 consecutive blocks. Nontemporal output stores.
__device__ __forceinline__ int swz(int row, int cc) {
  return row * 256 + ((cc ^ (row & 7)) << 4);
}

__global__ __launch_bounds__(256) void final_gemm4(const unsigned short* __restrict__ fcWb,
                                                   const unsigned short* __restrict__ h1b,
                                                   const float* __restrict__ bias,
                                                   float* __restrict__ out) {
  const int bid = blockIdx.x;
  const int x   = bid & 7;           // XCD
  const int j   = bid >> 3;          // [0,1024) per XCD
  const int mt  = j & 31;            // m-inner
  const int ntl = j >> 5;            // [0,32)
  const int nt  = x * 32 + ntl;
  if (nt >= 250) return;

  __shared__ alignas(16) char smem[32768];
  const int tid = threadIdx.x;
  const int bb = mt >> 2, tb = mt & 3;
  const int t0 = tb << 7;
  const int v0 = nt << 7;
  const int lane = tid & 63, wvv = tid >> 6;

  const char* gW = (const char*)fcWb + (size_t)v0 * 256;
#pragma unroll
  for (int it = 0; it < 8; ++it) {
    int cidx = it * 256 + tid;
    i32x4 vw = *(const i32x4*)(gW + cidx * 16);
    *(i32x4*)(smem + swz(cidx >> 4, cidx & 15)) = vw;
  }
  __syncthreads();

  const int l15 = lane & 15, lg = lane >> 4;
  f32x4 acc[8][2] = {};   // [vf][mf]
#pragma unroll
  for (int kk = 0; kk < 4; ++kk) {
    const int cc = kk * 4 + lg;
    s16x8 a[8], bfr[2];
#pragma unroll
    for (int vf = 0; vf < 8; ++vf)
      a[vf] = *(const s16x8*)(smem + swz(vf * 16 + l15, cc));
#pragma unroll
    for (int mf = 0; mf < 2; ++mf) {
      int trow = t0 + wvv * 32 + mf * 16 + l15;
      bfr[mf] = *(const s16x8*)(h1b + (size_t)((trow << 3) + bb) * H_ + kk * 32 + lg * 8);
    }
#pragma unroll
    for (int vf = 0; vf < 8; ++vf)
#pragma unroll
      for (int mf = 0; mf < 2; ++mf)
        acc[vf][mf] = __builtin_amdgcn_mfma_f32_16x16x32_bf16(a[vf], bfr[mf], acc[vf][mf], 0, 0, 0);
  }

  f32x4 bv[8];
#pragma unroll
  for (int vf = 0; vf < 8; ++vf)
    bv[vf] = *(const f32x4*)(bias + v0 + vf * 16 + (lg << 2));

#pragma unroll
  for (int mf = 0; mf < 2; ++mf) {
    const int trow = t0 + wvv * 32 + mf * 16 + l15;
    const size_t rowoff = (size_t)((bb << 9) + trow) * V_;
#pragma unroll
    for (int vf = 0; vf < 8; ++vf) {
      const int v = v0 + vf * 16 + (lg << 2);
      f32x4 val = acc[vf][mf] + bv[vf];
      __builtin_nontemporal_store(val, (f32x4*)(out + rowoff + v));
    }
  }
}

extern "C" void kernel_launch(void* const* d_in, const int* in_sizes, int n_in,
                              void* d_out, int out_size, void* d_ws, size_t ws_size,
                              hipStream_t stream) {
  const int*   x     = (const int*)d_in[0];
  const float* emb   = (const float*)d_in[1];
  const float* W_ih0 = (const float*)d_in[2];
  const float* W_hh0 = (const float*)d_in[3];
  const float* b_ih0 = (const float*)d_in[4];
  const float* b_hh0 = (const float*)d_in[5];
  const float* W_ih1 = (const float*)d_in[6];
  const float* W_hh1 = (const float*)d_in[7];
  const float* b_ih1 = (const float*)d_in[8];
  const float* b_hh1 = (const float*)d_in[9];
  const float* fc_W  = (const float*)d_in[10];
  const float* fc_b  = (const float*)d_in[11];
  float* out = (float*)d_out;

  char* ws = (char*)d_ws;
  float*          pre0 = (float*)ws;                          // 2 MB
  unsigned short* h1b  = (unsigned short*)(ws + (2u << 20));  // 1 MB
  unsigned short* fcWb = (unsigned short*)(ws + (3u << 20));  // 8 MB

  convert_w_kernel<<<1024, 256, 0, stream>>>(fc_W, fcWb, V_ * H_ / 4);
  pre_kernel<<<256, 128, 0, stream>>>(emb, x, W_ih0, b_ih0, b_hh0, pre0);
  fused_scan4<<<1, 768, 0, stream>>>(pre0, W_hh0, W_ih1, W_hh1, b_ih1, b_hh1, h1b);
  final_gemm4<<<8192, 256, 0, stream>>>(fcWb, h1b, fc_b, out);
}

// Round 6
// 475.423 us; speedup vs baseline: 1.2779x; 1.2779x over previous
//
#include <hip/hip_runtime.h>
#include <hip/hip_bf16.h>

typedef __attribute__((ext_vector_type(4))) float f32x4;
typedef __attribute__((ext_vector_type(4))) int   i32x4;
typedef __attribute__((ext_vector_type(8))) short s16x8;
typedef __attribute__((ext_vector_type(4))) unsigned short u16x4;
typedef __attribute__((ext_vector_type(2))) unsigned int  u32x2;
typedef __attribute__((ext_vector_type(2))) unsigned long long u64x2;

#define T_ 512
#define B_ 8
#define H_ 128
#define V_ 32000

// ws layout (bytes)
#define WS_PRE0   0u          // [512][8][128] f32   2MB
#define WS_H1B    (2u<<20)    // [512][8][128] bf16  1MB
#define WS_FCWB   (3u<<20)    // [32000][128] bf16   8MB
#define WS_PIH    (11u<<20)   // [512][8][64] f32x4  4MB (stored as u64 pairs)
#define WS_FLAGS  (15u<<20)   // prog1 u32 (memset 0 each launch)

// round-to-nearest-even f32 -> bf16
__device__ __forceinline__ unsigned short f2b(float f) {
  unsigned int u = __float_as_uint(f);
  u = (u + 0x7FFFu + ((u >> 16) & 1u)) >> 16;
  return (unsigned short)u;
}

__device__ __forceinline__ float hsum4(f32x4 v) { return (v.x + v.y) + (v.z + v.w); }

__device__ __forceinline__ float tanh_fast(float x) {
  float e = __expf(2.f * x);
  return 1.f - 2.f * __builtin_amdgcn_rcpf(e + 1.f);
}

__device__ __forceinline__ f32x4 tanh4(f32x4 v) {
  f32x4 r;
  r.x = tanh_fast(v.x); r.y = tanh_fast(v.y);
  r.z = tanh_fast(v.z); r.w = tanh_fast(v.w);
  return r;
}

// pack 4 f32 -> 4 bf16 (2 dwords)
__device__ __forceinline__ u32x2 pk4(f32x4 v) {
  unsigned int a, b;
  asm("v_cvt_pk_bf16_f32 %0, %1, %2" : "=v"(a) : "v"(v.x), "v"(v.y));
  asm("v_cvt_pk_bf16_f32 %0, %1, %2" : "=v"(b) : "v"(v.z), "v"(v.w));
  u32x2 r; r.x = a; r.y = b; return r;
}

// barrier that does NOT drain vmcnt: LDS-only visibility + s_barrier.
__device__ __forceinline__ void lds_barrier() {
  asm volatile("s_waitcnt lgkmcnt(0)\n\ts_barrier" ::: "memory");
}

// device-coherent (agent scope) helpers
__device__ __forceinline__ void st_u64(unsigned long long* p, unsigned long long v) {
  __hip_atomic_store(p, v, __ATOMIC_RELAXED, __HIP_MEMORY_SCOPE_AGENT);
}
__device__ __forceinline__ unsigned long long ld_u64(const unsigned long long* p) {
  return __hip_atomic_load(p, __ATOMIC_RELAXED, __HIP_MEMORY_SCOPE_AGENT);
}

#define MFMA16(A, B, C) __builtin_amdgcn_mfma_f32_16x16x32_bf16((A), (B), (C), 0, 0, 0)

// ---------------- pre0 = emb[x] @ W_ih0^T + b_ih0 + b_hh0 ----------------
__global__ __launch_bounds__(128) void pre_kernel(const float* __restrict__ emb,
                                                  const int* __restrict__ x,
                                                  const float* __restrict__ W,
                                                  const float* __restrict__ b1,
                                                  const float* __restrict__ b2,
                                                  float* __restrict__ out) {
  const int tid = threadIdx.x;
  __shared__ alignas(16) float lds_in[H_];
  f32x4 w[32];
#pragma unroll
  for (int r = 0; r < 32; ++r) w[r] = *(const f32x4*)(W + tid * H_ + 4 * r);
  const float bsum = b1[tid] + b2[tid];
  const int m0 = blockIdx.x * 16;

  auto src_row = [&](int m) -> const float* {
    int t = m >> 3, b = m & 7;
    int tok = x[(b << 9) + t];          // x is [B,T]
    return emb + (size_t)tok * H_;
  };

  float stage = src_row(m0)[tid];
  for (int rr = 0; rr < 16; ++rr) {
    const int m = m0 + rr;
    lds_in[tid] = stage;
    __syncthreads();
    if (rr + 1 < 16) stage = src_row(m0 + rr + 1)[tid];
    f32x4 acc4 = {0.f, 0.f, 0.f, 0.f};
#pragma unroll
    for (int r = 0; r < 32; ++r) {
      f32x4 hv = *(const f32x4*)(lds_in + 4 * r);
      acc4 = __builtin_elementwise_fma(hv, w[r], acc4);
    }
    out[m * H_ + tid] = hsum4(acc4) + bsum;
    __syncthreads();
  }
}

// ---------------- fused dual-layer scan, v5: multi-CU MFMA pipeline ----------------
// block 0 (8 waves): waves 0-3 = stage0 (h0 recurrence, W_hh0 hi/lo, 2 M-tiles/wave)
//                    waves 4-7 = stage1 (pih = W_ih1.h0 + b, hi-only, 2 M-tiles/wave)
//   h0 exchanged through LDS; pih published to global (agent atomics) with a
//   release fetch_add progress flag every 4 steps (vmcnt(0) drain amortized).
// block 1 (8 waves): stage2 (h1 recurrence, W_hh1 hi/lo, 1 M-tile/wave);
//   batched acquire-poll (x4) + depth-4 register FIFO of pih loads; writes h1b.
// blocks 2..65: fc_W f32->bf16 conversion on otherwise-idle CUs.
// Full-length pih buffer => producers never wait => deadlock-free by construction.
__global__ __launch_bounds__(512) __attribute__((amdgpu_waves_per_eu(2, 2)))
void fused_scan5(const float* __restrict__ pre0,
                 const float* __restrict__ W_hh0,
                 const float* __restrict__ W_ih1,
                 const float* __restrict__ W_hh1,
                 const float* __restrict__ b_ih1,
                 const float* __restrict__ b_hh1,
                 unsigned short* __restrict__ h1b,
                 unsigned long long* __restrict__ pih_g,
                 unsigned int* __restrict__ prog1,
                 const float* __restrict__ fcw_src,
                 unsigned short* __restrict__ fcw_dst) {
  const int bid = blockIdx.x;
  const int tid = threadIdx.x;

  if (bid >= 2) {           // ---- converter blocks (run concurrently) ----
    int idx = (bid - 2) * 512 + tid;
    const int stride = 64 * 512;
    const int n4 = V_ * H_ / 4;
    for (int c = idx; c < n4; c += stride) {
      f32x4 v = ((const f32x4*)fcw_src)[c];
      u16x4 o; o.x = f2b(v.x); o.y = f2b(v.y); o.z = f2b(v.z); o.w = f2b(v.w);
      ((u16x4*)fcw_dst)[c] = o;
    }
    return;
  }

  __shared__ unsigned short hl[2][16][136];
  const int wv = tid >> 6, lane = tid & 63;
  const int n = lane & 15, g = lane >> 4;
  const int nn = (n < 8) ? n : 7;
  for (int i = tid; i < 2 * 16 * 136; i += 512) ((unsigned short*)hl)[i] = 0;

  if (bid == 0) {
    // ================= stage 0 + stage 1 =================
    const bool is0 = wv < 4;
    const int w = wv & 3, m0 = w * 32;
    const float* Wm = is0 ? W_hh0 : W_ih1;
    s16x8 whi[2][4], wlo[2][4];
#pragma unroll
    for (int hf = 0; hf < 2; ++hf)
#pragma unroll
      for (int kt = 0; kt < 4; ++kt) {
        const float* src = Wm + (m0 + hf * 16 + n) * H_ + kt * 32 + g * 8;
        s16x8 hi, lo;
#pragma unroll
        for (int j = 0; j < 8; ++j) {
          float v = src[j];
          unsigned short hb = f2b(v);
          hi[j] = (short)hb;
          lo[j] = (short)f2b(v - __uint_as_float(((unsigned int)hb) << 16));
        }
        whi[hf][kt] = hi; wlo[hf][kt] = lo;
      }
    f32x4 c0b = {0.f,0.f,0.f,0.f}, c1b = {0.f,0.f,0.f,0.f};
    if (!is0) {
      c0b = *(const f32x4*)(b_ih1 + m0 + g * 4) + *(const f32x4*)(b_hh1 + m0 + g * 4);
      c1b = *(const f32x4*)(b_ih1 + m0 + 16 + g * 4) + *(const f32x4*)(b_hh1 + m0 + 16 + g * 4);
    }
    f32x4 fif[4][2];
    if (is0) {
#pragma unroll
      for (int k = 0; k < 4; ++k) {
        fif[k][0] = *(const f32x4*)(pre0 + (k * B_ + nn) * H_ + m0 + g * 4);
        fif[k][1] = *(const f32x4*)(pre0 + (k * B_ + nn) * H_ + m0 + 16 + g * 4);
      }
    }
    __syncthreads();

    for (int base = 0; base < T_; base += 4) {
#pragma unroll
      for (int k = 0; k < 4; ++k) {
        const int s = base + k;
        const int rd = (k + 1) & 1, wr = k & 1;
        const unsigned short* hb = &hl[rd][n][0];
        s16x8 b0 = *(const s16x8*)(hb + g * 8);
        s16x8 b1 = *(const s16x8*)(hb + 32 + g * 8);
        s16x8 b2 = *(const s16x8*)(hb + 64 + g * 8);
        s16x8 b3 = *(const s16x8*)(hb + 96 + g * 8);
        if (is0) {
          f32x4 aH0 = fif[k][0], aL0 = {0.f,0.f,0.f,0.f};
          f32x4 aH1 = fif[k][1], aL1 = {0.f,0.f,0.f,0.f};
          aH0 = MFMA16(whi[0][0], b0, aH0); aL0 = MFMA16(wlo[0][0], b0, aL0);
          aH0 = MFMA16(whi[0][1], b1, aH0); aL0 = MFMA16(wlo[0][1], b1, aL0);
          aH0 = MFMA16(whi[0][2], b2, aH0); aL0 = MFMA16(wlo[0][2], b2, aL0);
          aH0 = MFMA16(whi[0][3], b3, aH0); aL0 = MFMA16(wlo[0][3], b3, aL0);
          aH1 = MFMA16(whi[1][0], b0, aH1); aL1 = MFMA16(wlo[1][0], b0, aL1);
          aH1 = MFMA16(whi[1][1], b1, aH1); aL1 = MFMA16(wlo[1][1], b1, aL1);
          aH1 = MFMA16(whi[1][2], b2, aH1); aL1 = MFMA16(wlo[1][2], b2, aL1);
          aH1 = MFMA16(whi[1][3], b3, aH1); aL1 = MFMA16(wlo[1][3], b3, aL1);
          f32x4 v0 = tanh4(aH0 + aL0), v1 = tanh4(aH1 + aL1);
          *(u32x2*)&hl[wr][n][m0 + g * 4] = pk4(v0);
          *(u32x2*)&hl[wr][n][m0 + 16 + g * 4] = pk4(v1);
          int sp = s + 4; if (sp > T_ - 1) sp = T_ - 1;   // prefetch depth 4
          fif[k][0] = *(const f32x4*)(pre0 + (sp * B_ + nn) * H_ + m0 + g * 4);
          fif[k][1] = *(const f32x4*)(pre0 + (sp * B_ + nn) * H_ + m0 + 16 + g * 4);
        } else {
          if (k == 0 && base >= 4 && lane == 0)
            __hip_atomic_fetch_add(prog1, 4u, __ATOMIC_RELEASE, __HIP_MEMORY_SCOPE_AGENT);
          if (s >= 1) {
            f32x4 v0 = c0b, v1 = c1b;
            v0 = MFMA16(whi[0][0], b0, v0); v1 = MFMA16(whi[1][0], b0, v1);
            v0 = MFMA16(whi[0][1], b1, v0); v1 = MFMA16(whi[1][1], b1, v1);
            v0 = MFMA16(whi[0][2], b2, v0); v1 = MFMA16(whi[1][2], b2, v1);
            v0 = MFMA16(whi[0][3], b3, v0); v1 = MFMA16(whi[1][3], b3, v1);
            u64x2 u0 = __builtin_bit_cast(u64x2, v0);
            u64x2 u1 = __builtin_bit_cast(u64x2, v1);
            unsigned long long* p0 = pih_g + ((size_t)((s - 1) * 8 + 2 * w) * 64 + lane) * 2;
            st_u64(p0, u0.x); st_u64(p0 + 1, u0.y);
            unsigned long long* p1 = pih_g + ((size_t)((s - 1) * 8 + 2 * w + 1) * 64 + lane) * 2;
            st_u64(p1, u1.x); st_u64(p1 + 1, u1.y);
          }
        }
        lds_barrier();
      }
    }
    // tail region s = 512: stage1 computes pih[511], final release
    if (!is0) {
      const unsigned short* hb = &hl[1][n][0];   // written at region 511
      s16x8 b0 = *(const s16x8*)(hb + g * 8);
      s16x8 b1 = *(const s16x8*)(hb + 32 + g * 8);
      s16x8 b2 = *(const s16x8*)(hb + 64 + g * 8);
      s16x8 b3 = *(const s16x8*)(hb + 96 + g * 8);
      f32x4 v0 = c0b, v1 = c1b;
      v0 = MFMA16(whi[0][0], b0, v0); v1 = MFMA16(whi[1][0], b0, v1);
      v0 = MFMA16(whi[0][1], b1, v0); v1 = MFMA16(whi[1][1], b1, v1);
      v0 = MFMA16(whi[0][2], b2, v0); v1 = MFMA16(whi[1][2], b2, v1);
      v0 = MFMA16(whi[0][3], b3, v0); v1 = MFMA16(whi[1][3], b3, v1);
      u64x2 u0 = __builtin_bit_cast(u64x2, v0);
      u64x2 u1 = __builtin_bit_cast(u64x2, v1);
      unsigned long long* p0 = pih_g + ((size_t)(511 * 8 + 2 * w) * 64 + lane) * 2;
      st_u64(p0, u0.x); st_u64(p0 + 1, u0.y);
      unsigned long long* p1 = pih_g + ((size_t)(511 * 8 + 2 * w + 1) * 64 + lane) * 2;
      st_u64(p1, u1.x); st_u64(p1 + 1, u1.y);
      if (lane == 0)
        __hip_atomic_fetch_add(prog1, 16u, __ATOMIC_RELEASE, __HIP_MEMORY_SCOPE_AGENT);
    }
  } else {
    // ================= stage 2 =================
    const int m0 = wv * 16;    // 8 waves, 1 M-tile each
    s16x8 whi[4], wlo[4];
#pragma unroll
    for (int kt = 0; kt < 4; ++kt) {
      const float* src = W_hh1 + (m0 + n) * H_ + kt * 32 + g * 8;
      s16x8 hi, lo;
#pragma unroll
      for (int j = 0; j < 8; ++j) {
        float v = src[j];
        unsigned short hb = f2b(v);
        hi[j] = (short)hb;
        lo[j] = (short)f2b(v - __uint_as_float(((unsigned int)hb) << 16));
      }
      whi[kt] = hi; wlo[kt] = lo;
    }
    __syncthreads();

    auto ld_pih = [&](int step) -> f32x4 {
      const unsigned long long* p = pih_g + ((size_t)(step * 8 + wv) * 64 + lane) * 2;
      u64x2 u; u.x = ld_u64(p); u.y = ld_u64(p + 1);
      return __builtin_bit_cast(f32x4, u);
    };
    // prefill: need pih[0..3] => prog1 >= 4*(3+2)
    while (__hip_atomic_load(prog1, __ATOMIC_ACQUIRE, __HIP_MEMORY_SCOPE_AGENT) < 20u)
      __builtin_amdgcn_s_sleep(2);
    f32x4 fif[4];
#pragma unroll
    for (int k = 0; k < 4; ++k) fif[k] = ld_pih(k);

    for (int base = 0; base < T_; base += 4) {
      if (base + 4 < T_) {   // will issue loads for base+4..base+7: need coverage base+7
        const unsigned int t = 4u * (unsigned)(base + 9);
        while (__hip_atomic_load(prog1, __ATOMIC_ACQUIRE, __HIP_MEMORY_SCOPE_AGENT) < t)
          __builtin_amdgcn_s_sleep(2);
      }
#pragma unroll
      for (int k = 0; k < 4; ++k) {
        const int j = base + k;
        const int rd = (k + 1) & 1, wr = k & 1;
        const unsigned short* hb = &hl[rd][n][0];
        s16x8 b0 = *(const s16x8*)(hb + g * 8);
        s16x8 b1 = *(const s16x8*)(hb + 32 + g * 8);
        s16x8 b2 = *(const s16x8*)(hb + 64 + g * 8);
        s16x8 b3 = *(const s16x8*)(hb + 96 + g * 8);
        f32x4 aH = fif[k], aL = {0.f,0.f,0.f,0.f};
        aH = MFMA16(whi[0], b0, aH); aL = MFMA16(wlo[0], b0, aL);
        aH = MFMA16(whi[1], b1, aH); aL = MFMA16(wlo[1], b1, aL);
        aH = MFMA16(whi[2], b2, aH); aL = MFMA16(wlo[2], b2, aL);
        aH = MFMA16(whi[3], b3, aH); aL = MFMA16(wlo[3], b3, aL);
        f32x4 v = tanh4(aH + aL);
        u32x2 o = pk4(v);
        *(u32x2*)&hl[wr][n][m0 + g * 4] = o;
        if (n < 8) *(u32x2*)(h1b + ((j * B_ + n) << 7) + m0 + g * 4) = o;
        if (j + 4 < T_) fif[k] = ld_pih(j + 4);
        lds_barrier();
      }
    }
  }
}

// ---------------- logits = h1 @ fc_W^T + fc_b (bf16 MFMA, v5) ----------------
// XCD-chunked grid; LDS-transposed epilogue so each global store instruction
// writes 4 x 256B contiguous row segments (v4 wrote 16 x 64B -> ~half write BW).
__device__ __forceinline__ int swz(int row, int cc) {
  return row * 256 + ((cc ^ (row & 7)) << 4);
}

__global__ __launch_bounds__(256) void final_gemm5(const unsigned short* __restrict__ fcWb,
                                                   const unsigned short* __restrict__ h1b,
                                                   const float* __restrict__ bias,
                                                   float* __restrict__ out) {
  const int bid = blockIdx.x;
  const int x   = bid & 7;
  const int jb  = bid >> 3;
  const int mt  = jb & 31;
  const int ntl = jb >> 5;
  const int nt  = x * 32 + ntl;
  if (nt >= 250) return;

  __shared__ alignas(16) char smem[33792];   // W-stage 32KB | f32[128][66] transpose
  const int tid = threadIdx.x;
  const int bb = mt >> 2, tb = mt & 3;
  const int t0 = tb << 7;
  const int v0 = nt << 7;
  const int lane = tid & 63, wvv = tid >> 6;

  const char* gW = (const char*)fcWb + (size_t)v0 * 256;
#pragma unroll
  for (int it = 0; it < 8; ++it) {
    int cidx = it * 256 + tid;
    i32x4 vw = *(const i32x4*)(gW + cidx * 16);
    *(i32x4*)(smem + swz(cidx >> 4, cidx & 15)) = vw;
  }
  __syncthreads();

  const int l15 = lane & 15, lg = lane >> 4;
  f32x4 acc[8][2] = {};   // [vf][mf]
#pragma unroll
  for (int kk = 0; kk < 4; ++kk) {
    const int cc = kk * 4 + lg;
    s16x8 a[8], bfr[2];
#pragma unroll
    for (int vf = 0; vf < 8; ++vf)
      a[vf] = *(const s16x8*)(smem + swz(vf * 16 + l15, cc));
#pragma unroll
    for (int mf = 0; mf < 2; ++mf) {
      int trow = t0 + wvv * 32 + mf * 16 + l15;
      bfr[mf] = *(const s16x8*)(h1b + (size_t)((trow << 3) + bb) * H_ + kk * 32 + lg * 8);
    }
#pragma unroll
    for (int vf = 0; vf < 8; ++vf)
#pragma unroll
      for (int mf = 0; mf < 2; ++mf)
        acc[vf][mf] = __builtin_amdgcn_mfma_f32_16x16x32_bf16(a[vf], bfr[mf], acc[vf][mf], 0, 0, 0);
  }

#pragma unroll
  for (int vf = 0; vf < 8; ++vf) {
    f32x4 bv = *(const f32x4*)(bias + v0 + vf * 16 + (lg << 2));
#pragma unroll
    for (int mf = 0; mf < 2; ++mf) acc[vf][mf] += bv;
  }

  float* tbf = (float*)smem;
#pragma unroll
  for (int p = 0; p < 2; ++p) {
    __syncthreads();
#pragma unroll
    for (int q = 0; q < 4; ++q) {
      const int vf = p * 4 + q;
#pragma unroll
      for (int mf = 0; mf < 2; ++mf) {
        int t = wvv * 32 + mf * 16 + l15;
        int vl = q * 16 + lg * 4;
        *(f32x4*)(tbf + t * 66 + vl) = acc[vf][mf];
      }
    }
    __syncthreads();
#pragma unroll
    for (int it = 0; it < 8; ++it) {
      int row = it * 16 + (tid >> 4);
      int col = (tid & 15) * 4;
      f32x4 val = *(const f32x4*)(tbf + row * 66 + col);
      const size_t off = (size_t)((bb << 9) + t0 + row) * V_ + v0 + p * 64 + col;
      __builtin_nontemporal_store(val, (f32x4*)(out + off));
    }
  }
}

extern "C" void kernel_launch(void* const* d_in, const int* in_sizes, int n_in,
                              void* d_out, int out_size, void* d_ws, size_t ws_size,
                              hipStream_t stream) {
  const int*   x     = (const int*)d_in[0];
  const float* emb   = (const float*)d_in[1];
  const float* W_ih0 = (const float*)d_in[2];
  const float* W_hh0 = (const float*)d_in[3];
  const float* b_ih0 = (const float*)d_in[4];
  const float* b_hh0 = (const float*)d_in[5];
  const float* W_ih1 = (const float*)d_in[6];
  const float* W_hh1 = (const float*)d_in[7];
  const float* b_ih1 = (const float*)d_in[8];
  const float* b_hh1 = (const float*)d_in[9];
  const float* fc_W  = (const float*)d_in[10];
  const float* fc_b  = (const float*)d_in[11];
  float* out = (float*)d_out;

  char* ws = (char*)d_ws;
  float*              pre0  = (float*)(ws + WS_PRE0);
  unsigned short*     h1b   = (unsigned short*)(ws + WS_H1B);
  unsigned short*     fcWb  = (unsigned short*)(ws + WS_FCWB);
  unsigned long long* pih_g = (unsigned long long*)(ws + WS_PIH);
  unsigned int*       prog1 = (unsigned int*)(ws + WS_FLAGS);

  hipMemsetAsync(ws + WS_FLAGS, 0, 4096, stream);
  pre_kernel<<<256, 128, 0, stream>>>(emb, x, W_ih0, b_ih0, b_hh0, pre0);
  fused_scan5<<<66, 512, 0, stream>>>(pre0, W_hh0, W_ih1, W_hh1, b_ih1, b_hh1,
                                      h1b, pih_g, prog1, fc_W, fcWb);
  final_gemm5<<<8192, 256, 0, stream>>>(fcWb, h1b, fc_b, out);
}